// Round 6
// baseline (137.286 us; speedup 1.0000x reference)
//
#include <hip/hip_runtime.h>
#include <hip/hip_fp16.h>

// Warp: trilinear grid_sample, padding_mode='zeros', align_corners=true.
// image: (B=2, C=1, H=128, W=128, D=128) fp32
// ddf:   (B=2, 3, H, W, D) fp32 voxel displacements; out: (B,1,H,W,D) fp32
//
// R5 post-mortem: barrier-phased blocks serialize memory phase (stage 176KB)
// and compute phase (LDS taps) -> HBM 23%, VALU 16%, both pipes half-idle.
// R6: persistent blocks (1/CU, 1024 thr), 4 z-adjacent 16^3 tiles each,
// double-buffered 2x64KB dynamic LDS. Tile k+1's global loads are in flight
// (VGPRs) during tile k's compute; convert+ds_write into the other buffer
// after compute; one barrier per tile. HBM streams continuously.

constexpr int H = 128, W = 128, D = 128;
constexpr int N = H * W * D;      // 2^21
constexpr int B = 2;
constexpr int HA = 8;             // halo per side
constexpr int RS = 32;            // region edge
constexpr int RN = RS * RS * RS;  // 32768 fp16 = 64 KB per buffer

typedef unsigned short us4 __attribute__((ext_vector_type(4)));

__device__ __forceinline__ void decode_tile(int T, int& b, int& tx0, int& ty0, int& tz0) {
    b = T >> 9;
    int t3 = T & 511;
    tx0 = ((t3 >> 6) & 7) << 4;
    ty0 = ((t3 >> 3) & 7) << 4;
    tz0 = (t3 & 7) << 4;
}

__device__ __forceinline__ void issue_ddf(const float* __restrict__ ddf,
    int b, int tx0, int ty0, int tz0, int t,
    float dx[4], float dy[4], float dz[4])
{
    const float* ddfb = ddf + (size_t)b * 3 * N;
    int lz = t & 15, ly = (t >> 4) & 15, xb = (t >> 8) << 2;
    int yz = ((ty0 + ly) << 7) + (tz0 + lz);
#pragma unroll
    for (int i = 0; i < 4; ++i) {
        int lin = ((tx0 + xb + i) << 14) + yz;
        dx[i] = ddfb[lin];
        dy[i] = ddfb[lin + N];
        dz[i] = ddfb[lin + 2 * N];
    }
}

__device__ __forceinline__ void issue_stage(const float* __restrict__ image,
    int b, int tx0, int ty0, int tz0, int t, float4 stg[8])
{
    const float* img = image + ((size_t)b << 21);
    int ox = tx0 - HA, oy = ty0 - HA, oz = tz0 - HA;
#pragma unroll
    for (int i = 0; i < 8; ++i) {
        int f   = i * 1024 + t;
        int row = f >> 3;             // rx*32 + ry, in [0,1024)
        int zi  = (f & 7) << 2;
        int gx = ox + (row >> 5);
        int gy = oy + (row & 31);
        int gz = oz + zi;
        float4 v = make_float4(0.f, 0.f, 0.f, 0.f);
        if ((unsigned)gx < 128u && (unsigned)gy < 128u && (unsigned)gz < 128u)
            v = *(const float4*)(img + (gx << 14) + (gy << 7) + gz);
        stg[i] = v;
    }
}

__device__ __forceinline__ void write_stage(__half* buf, int t, const float4 stg[8])
{
    unsigned short* tp = (unsigned short*)buf;
#pragma unroll
    for (int i = 0; i < 8; ++i) {
        int f   = i * 1024 + t;
        int row = f >> 3;
        int zi  = (f & 7) << 2;
        us4 p;
        p.x = __half_as_ushort(__float2half_rn(stg[i].x));
        p.y = __half_as_ushort(__float2half_rn(stg[i].y));
        p.z = __half_as_ushort(__float2half_rn(stg[i].z));
        p.w = __half_as_ushort(__float2half_rn(stg[i].w));
        *(us4*)(tp + row * 32 + zi) = p;   // 8B ds_write_b64
    }
}

__device__ __forceinline__ void compute_tile(const __half* __restrict__ buf,
    const float* __restrict__ image, float* __restrict__ out,
    int b, int tx0, int ty0, int tz0, int t,
    const float dx[4], const float dy[4], const float dz[4])
{
    const float* img = image + ((size_t)b << 21);
    float* outb = out + ((size_t)b << 21);
    int lz = t & 15, ly = (t >> 4) & 15, xb = (t >> 8) << 2;
    int ox = tx0 - HA, oy = ty0 - HA, oz = tz0 - HA;
    int yz = ((ty0 + ly) << 7) + (tz0 + lz);
    float py = (float)(ty0 + ly);
    float pz = (float)(tz0 + lz);

#pragma unroll
    for (int i = 0; i < 4; ++i) {
        int lin = ((tx0 + xb + i) << 14) + yz;
        float x = (float)(tx0 + xb + i) + dx[i];
        float y = py + dy[i];
        float z = pz + dz[i];

        float xf = floorf(x), yf = floorf(y), zf = floorf(z);
        float fx = x - xf, fy = y - yf, fz = z - zf;
        int x0 = (int)xf, y0 = (int)yf, z0 = (int)zf;
        int rx = x0 - ox, ry = y0 - oy, rz = z0 - oz;

        float acc;
        if ((unsigned)rx <= 30u && (unsigned)ry <= 30u && (unsigned)rz <= 30u) {
            const __half* base = buf + ((rx << 5) + ry) * 32 + rz;
            float v000 = __half2float(base[0]);
            float v001 = __half2float(base[1]);
            float v010 = __half2float(base[32]);
            float v011 = __half2float(base[33]);
            float v100 = __half2float(base[1024]);
            float v101 = __half2float(base[1025]);
            float v110 = __half2float(base[1056]);
            float v111 = __half2float(base[1057]);
            float ax0 = 1.f - fx, ay0 = 1.f - fy, az0 = 1.f - fz;
            acc = ax0 * (ay0 * (az0 * v000 + fz * v001) +
                         fy  * (az0 * v010 + fz * v011)) +
                  fx  * (ay0 * (az0 * v100 + fz * v101) +
                         fy  * (az0 * v110 + fz * v111));
        } else {
            // rare (~0.1%): exact fp32 global gather with zero-padding.
            int x1 = x0 + 1, y1 = y0 + 1, z1 = z0 + 1;
            bool vx0 = (unsigned)x0 < (unsigned)H;
            bool vx1 = (unsigned)x1 < (unsigned)H;
            bool vy0 = (unsigned)y0 < (unsigned)W;
            bool vy1 = (unsigned)y1 < (unsigned)W;
            bool vz0 = (unsigned)z0 < (unsigned)D;
            bool vz1 = (unsigned)z1 < (unsigned)D;
            float ax0 = vx0 ? (1.0f - fx) : 0.0f;
            float ax1 = vx1 ? fx          : 0.0f;
            float ay0 = vy0 ? (1.0f - fy) : 0.0f;
            float ay1 = vy1 ? fy          : 0.0f;
            float az0 = vz0 ? (1.0f - fz) : 0.0f;
            float az1 = vz1 ? fz          : 0.0f;
            int cx0 = vx0 ? x0 : 0;
            int cx1 = vx1 ? x1 : 0;
            int cy0 = vy0 ? y0 : 0;
            int cy1 = vy1 ? y1 : 0;
            int cz0 = vz0 ? z0 : 0;
            int cz1 = vz1 ? z1 : 0;
            int rx0 = cx0 << 14, rx1 = cx1 << 14;
            int ry0 = cy0 << 7,  ry1 = cy1 << 7;
            float v000 = img[rx0 + ry0 + cz0];
            float v001 = img[rx0 + ry0 + cz1];
            float v010 = img[rx0 + ry1 + cz0];
            float v011 = img[rx0 + ry1 + cz1];
            float v100 = img[rx1 + ry0 + cz0];
            float v101 = img[rx1 + ry0 + cz1];
            float v110 = img[rx1 + ry1 + cz0];
            float v111 = img[rx1 + ry1 + cz1];
            acc = ax0 * (ay0 * (az0 * v000 + az1 * v001) +
                         ay1 * (az0 * v010 + az1 * v011)) +
                  ax1 * (ay0 * (az0 * v100 + az1 * v101) +
                         ay1 * (az0 * v110 + az1 * v111));
        }
        __builtin_nontemporal_store(acc, &outb[lin]);
    }
}

__global__ __launch_bounds__(1024, 4) void warp_persist_kernel(
    const float* __restrict__ image,
    const float* __restrict__ ddf,
    float* __restrict__ out)
{
    extern __shared__ __half smem[];   // 2 * RN halves = 128 KB
    int t = threadIdx.x;
    int T0 = blockIdx.x * 4;           // 4 consecutive (z-adjacent) tiles

    int bs[4], xs[4], ys[4], zs[4];
#pragma unroll
    for (int k = 0; k < 4; ++k) decode_tile(T0 + k, bs[k], xs[k], ys[k], zs[k]);

    float4 stg[8];
    float dx[2][4], dy[2][4], dz[2][4];

    // Prologue: fill buf0 with tile 0; leave tile 1's loads in flight.
    issue_ddf(ddf, bs[0], xs[0], ys[0], zs[0], t, dx[0], dy[0], dz[0]);
    issue_stage(image, bs[0], xs[0], ys[0], zs[0], t, stg);
    write_stage(smem, t, stg);
    issue_ddf(ddf, bs[1], xs[1], ys[1], zs[1], t, dx[1], dy[1], dz[1]);
    issue_stage(image, bs[1], xs[1], ys[1], zs[1], t, stg);
    __syncthreads();

#pragma unroll
    for (int k = 0; k < 4; ++k) {
        compute_tile(smem + (k & 1) * RN, image, out,
                     bs[k], xs[k], ys[k], zs[k], t, dx[k & 1], dy[k & 1], dz[k & 1]);
        if (k < 3) {
            // stg holds tile k+1 (loads had the whole compute phase to land)
            write_stage(smem + ((k + 1) & 1) * RN, t, stg);
            if (k < 2) {
                issue_ddf(ddf, bs[k + 2], xs[k + 2], ys[k + 2], zs[k + 2], t,
                          dx[k & 1], dy[k & 1], dz[k & 1]);
                issue_stage(image, bs[k + 2], xs[k + 2], ys[k + 2], zs[k + 2], t, stg);
            }
            __syncthreads();
        }
    }
}

// ---- Fallback (R5 path) if >64KB dynamic LDS opt-in fails ----
__global__ __launch_bounds__(1024, 6) void warp_tile_kernel(
    const float* __restrict__ image,
    const float* __restrict__ ddf,
    float* __restrict__ out)
{
    __shared__ __half tile[RN];
    int bid = blockIdx.x;
    int b  = bid >> 9;
    int t3 = bid & 511;
    int tx0 = ((t3 >> 6) & 7) << 4;
    int ty0 = ((t3 >> 3) & 7) << 4;
    int tz0 = (t3 & 7) << 4;
    int t = threadIdx.x;

    float dx[4], dy[4], dz[4];
    issue_ddf(ddf, b, tx0, ty0, tz0, t, dx, dy, dz);
    float4 stg[8];
    issue_stage(image, b, tx0, ty0, tz0, t, stg);
    write_stage(tile, t, stg);
    __syncthreads();
    compute_tile(tile, image, out, b, tx0, ty0, tz0, t, dx, dy, dz);
}

extern "C" void kernel_launch(void* const* d_in, const int* in_sizes, int n_in,
                              void* d_out, int out_size, void* d_ws, size_t ws_size,
                              hipStream_t stream) {
    const float* image = (const float*)d_in[0];
    const float* ddf   = (const float*)d_in[1];
    float* out = (float*)d_out;

    size_t shmem = (size_t)2 * RN * sizeof(__half);   // 131072
    hipError_t e = hipFuncSetAttribute(
        reinterpret_cast<const void*>(warp_persist_kernel),
        hipFuncAttributeMaxDynamicSharedMemorySize, (int)shmem);
    if (e == hipSuccess) {
        warp_persist_kernel<<<256, 1024, shmem, stream>>>(image, ddf, out);
    } else {
        warp_tile_kernel<<<B * 512, 1024, 0, stream>>>(image, ddf, out);
    }
}

// Round 8
// 113.373 us; speedup vs baseline: 1.2109x; 1.2109x over previous
//
#include <hip/hip_runtime.h>
#include <hip/hip_fp16.h>

// Warp: trilinear grid_sample, padding_mode='zeros', align_corners=true.
// image: (B=2, C=1, H=128, W=128, D=128) fp32
// ddf:   (B=2, 3, H, W, D) fp32 voxel displacements; out: (B,1,H,W,D) fp32
//
// Model (fits R1/R3/R5/R6): runtime ~ per-lane memory INSTRUCTIONS at
// ~1 lane-instr/cy/CU (vmem + LDS summed when barrier-serialized).
// R7 = R5 tile structure with every memory touch vectorized:
//  - thread handles 4 consecutive z voxels: ddf 3x float4, out 1x float4
//  - staging via 32B slots: 8 float4 loads + 4 ds_write_b128
//  - taps via ds_read_b64 (4 z-halves) + funnel shift; u16 top-up only when
//    rz&3==3.

constexpr int H = 128, W = 128, D = 128;
constexpr int N = H * W * D;      // 2^21
constexpr int B = 2;
constexpr int HA = 8;             // halo per side
constexpr int RS = 32;            // region edge
constexpr int RN = RS * RS * RS;  // 32768 fp16 = 64 KB

typedef float fvec4 __attribute__((ext_vector_type(4)));

__global__ __launch_bounds__(1024, 8) void warp_tile_kernel(
    const float* __restrict__ image,
    const float* __restrict__ ddf,
    float* __restrict__ out)
{
    __shared__ __half tile[RN];   // 64 KB -> 2 blocks/CU

    int bid = blockIdx.x;
    int b  = bid >> 9;            // 512 tiles per batch
    int t3 = bid & 511;
    int tx0 = ((t3 >> 6) & 7) << 4;
    int ty0 = ((t3 >> 3) & 7) << 4;
    int tz0 = (t3 & 7) << 4;
    int ox = tx0 - HA, oy = ty0 - HA, oz = tz0 - HA;

    const float* img = image + ((size_t)b << 21);
    int t = threadIdx.x;          // 0..1023

    // ---- thread -> 4 consecutive z voxels ----
    int zq = (t & 3) << 2;        // 0,4,8,12
    int ly = (t >> 2) & 15;
    int lx = t >> 6;
    int vx = tx0 + lx, vy = ty0 + ly, vz = tz0 + zq;
    int lin0 = (vx << 14) + (vy << 7) + vz;      // 16B aligned

    // ddf prefetch: 3 vector loads (issue before staging; used after barrier)
    const float* ddfb = ddf + (size_t)b * 3 * N;
    fvec4 dx4 = *(const fvec4*)(ddfb + lin0);
    fvec4 dy4 = *(const fvec4*)(ddfb + lin0 + N);
    fvec4 dz4 = *(const fvec4*)(ddfb + lin0 + 2 * N);

    // ---- stage 32^3 region as fp16 (zeros outside volume) ----
    // 4096 32-byte slots; slot s: row = s>>2 (rx*32+ry), zo = (s&3)*8.
    // oz ≡ 0 mod 8 -> each 8-float chunk is fully inside or fully outside.
    fvec4 sa[4], sb[4];
    int rows[4], zos[4];
#pragma unroll
    for (int c = 0; c < 4; ++c) {
        int s   = c * 1024 + t;
        int row = s >> 2;
        int zo  = (s & 3) << 3;
        rows[c] = row; zos[c] = zo;
        int gx = ox + (row >> 5);
        int gy = oy + (row & 31);
        int gz = oz + zo;
        bool ok = ((unsigned)gx < 128u) & ((unsigned)gy < 128u) & ((unsigned)gz < 121u);
        const float* p = img + (gx << 14) + (gy << 7) + gz;
        fvec4 z4 = {0.f, 0.f, 0.f, 0.f};
        sa[c] = ok ? *(const fvec4*)p       : z4;
        sb[c] = ok ? *(const fvec4*)(p + 4) : z4;
    }
    unsigned short* tp = (unsigned short*)tile;
#pragma unroll
    for (int c = 0; c < 4; ++c) {
        __half2 h0 = __floats2half2_rn(sa[c].x, sa[c].y);
        __half2 h1 = __floats2half2_rn(sa[c].z, sa[c].w);
        __half2 h2 = __floats2half2_rn(sb[c].x, sb[c].y);
        __half2 h3 = __floats2half2_rn(sb[c].z, sb[c].w);
        uint4 pk;
        pk.x = *(unsigned int*)&h0;
        pk.y = *(unsigned int*)&h1;
        pk.z = *(unsigned int*)&h2;
        pk.w = *(unsigned int*)&h3;
        *(uint4*)(tp + rows[c] * 32 + zos[c]) = pk;   // ds_write_b128
    }
    __syncthreads();

    // ---- compute 4 outputs (consecutive z), one float4 store ----
    float* outb = out + ((size_t)b << 21);
    const unsigned short* tpu = (const unsigned short*)tile;
    float dxp[4] = {dx4.x, dx4.y, dx4.z, dx4.w};
    float dyp[4] = {dy4.x, dy4.y, dy4.z, dy4.w};
    float dzp[4] = {dz4.x, dz4.y, dz4.z, dz4.w};
    float res[4];

#pragma unroll
    for (int i = 0; i < 4; ++i) {
        float x = (float)vx + dxp[i];
        float y = (float)vy + dyp[i];
        float z = (float)(vz + i) + dzp[i];

        float xf = floorf(x), yf = floorf(y), zf = floorf(z);
        float fx = x - xf, fy = y - yf, fz = z - zf;
        int x0 = (int)xf, y0 = (int)yf, z0 = (int)zf;
        int rx = x0 - ox, ry = y0 - oy, rz = z0 - oz;

        float acc;
        if ((unsigned)rx <= 30u && (unsigned)ry <= 30u && (unsigned)rz <= 30u) {
            // fast path: staged zeros implement zero-padding exactly.
            int base = ((rx << 5) + ry) << 5;
            int b4 = rz & ~3;
            int j  = rz & 3;
            float lo[4], hi[4];
#pragma unroll
            for (int p2 = 0; p2 < 4; ++p2) {
                int idx = base + ((p2 >> 1) << 10) + ((p2 & 1) << 5) + b4;
                uint2 q = *(const uint2*)(tpu + idx);      // ds_read_b64, 8B aligned
                unsigned int pr;
                if (j < 3) {
                    unsigned long long v = ((unsigned long long)q.y << 32) | q.x;
                    pr = (unsigned int)(v >> (j * 16));
                } else {
                    pr = (q.y >> 16) | ((unsigned int)tpu[idx + 4] << 16);
                }
                __half2 hp = *(__half2*)&pr;
                float2 f2 = __half22float2(hp);
                lo[p2] = f2.x; hi[p2] = f2.y;
            }
            float az0 = 1.f - fz;
            float z00 = az0 * lo[0] + fz * hi[0];
            float z01 = az0 * lo[1] + fz * hi[1];
            float z10 = az0 * lo[2] + fz * hi[2];
            float z11 = az0 * lo[3] + fz * hi[3];
            float ay0 = 1.f - fy;
            acc = (1.f - fx) * (ay0 * z00 + fy * z01) +
                  fx         * (ay0 * z10 + fy * z11);
        } else {
            // rare (~0.1%): exact fp32 global gather with zero-padding.
            int x1 = x0 + 1, y1 = y0 + 1, z1 = z0 + 1;
            bool vx0 = (unsigned)x0 < (unsigned)H;
            bool vx1 = (unsigned)x1 < (unsigned)H;
            bool vy0 = (unsigned)y0 < (unsigned)W;
            bool vy1 = (unsigned)y1 < (unsigned)W;
            bool vz0 = (unsigned)z0 < (unsigned)D;
            bool vz1 = (unsigned)z1 < (unsigned)D;
            float ax0 = vx0 ? (1.0f - fx) : 0.0f;
            float ax1 = vx1 ? fx          : 0.0f;
            float ay0 = vy0 ? (1.0f - fy) : 0.0f;
            float ay1 = vy1 ? fy          : 0.0f;
            float az0 = vz0 ? (1.0f - fz) : 0.0f;
            float az1 = vz1 ? fz          : 0.0f;
            int cx0 = vx0 ? x0 : 0;
            int cx1 = vx1 ? x1 : 0;
            int cy0 = vy0 ? y0 : 0;
            int cy1 = vy1 ? y1 : 0;
            int cz0 = vz0 ? z0 : 0;
            int cz1 = vz1 ? z1 : 0;
            int rx0 = cx0 << 14, rx1 = cx1 << 14;
            int ry0 = cy0 << 7,  ry1 = cy1 << 7;
            float v000 = img[rx0 + ry0 + cz0];
            float v001 = img[rx0 + ry0 + cz1];
            float v010 = img[rx0 + ry1 + cz0];
            float v011 = img[rx0 + ry1 + cz1];
            float v100 = img[rx1 + ry0 + cz0];
            float v101 = img[rx1 + ry0 + cz1];
            float v110 = img[rx1 + ry1 + cz0];
            float v111 = img[rx1 + ry1 + cz1];
            acc = ax0 * (ay0 * (az0 * v000 + az1 * v001) +
                         ay1 * (az0 * v010 + az1 * v011)) +
                  ax1 * (ay0 * (az0 * v100 + az1 * v101) +
                         ay1 * (az0 * v110 + az1 * v111));
        }
        res[i] = acc;
    }
    fvec4 r4 = {res[0], res[1], res[2], res[3]};
    __builtin_nontemporal_store(r4, (fvec4*)(outb + lin0));
}

extern "C" void kernel_launch(void* const* d_in, const int* in_sizes, int n_in,
                              void* d_out, int out_size, void* d_ws, size_t ws_size,
                              hipStream_t stream) {
    const float* image = (const float*)d_in[0];
    const float* ddf   = (const float*)d_in[1];
    float* out = (float*)d_out;

    warp_tile_kernel<<<B * 512, 1024, 0, stream>>>(image, ddf, out);
}

// Round 9
// 111.959 us; speedup vs baseline: 1.2262x; 1.0126x over previous
//
#include <hip/hip_runtime.h>
#include <hip/hip_fp16.h>

// Warp: trilinear grid_sample, padding_mode='zeros', align_corners=true.
// image: (B=2, C=1, H=128, W=128, D=128) fp32
// ddf:   (B=2, 3, H, W, D) fp32 voxel displacements; out: (B,1,H,W,D) fp32
//
// Lane-slot model (fits R1..R8): runtime ~ per-lane memory instruction slots
// at ~1/cy/CU. R8 = 48 slots/thread -> 37us. R9 cuts the tap path:
// fp16 tile read as dword-aligned half2 cells; z-pair = 2 adjacent b32 reads
// (-> ds_read2_b32) + 64-bit shift. Kills the always-issued masked u16
// top-up and the alignment branch: 32 slots/thread -> predicted ~26-29us.

constexpr int H = 128, W = 128, D = 128;
constexpr int N = H * W * D;      // 2^21
constexpr int B = 2;
constexpr int HA = 8;             // halo per side
constexpr int RS = 32;            // region edge
constexpr int RN = RS * RS * RS;  // 32768 fp16 = 64 KB

typedef float fvec4 __attribute__((ext_vector_type(4)));

__global__ __launch_bounds__(1024, 8) void warp_tile_kernel(
    const float* __restrict__ image,
    const float* __restrict__ ddf,
    float* __restrict__ out)
{
    __shared__ __half tile[RN];   // 64 KB -> 2 blocks/CU

    int bid = blockIdx.x;
    int b  = bid >> 9;            // 512 tiles per batch
    int t3 = bid & 511;
    int tx0 = ((t3 >> 6) & 7) << 4;
    int ty0 = ((t3 >> 3) & 7) << 4;
    int tz0 = (t3 & 7) << 4;
    int ox = tx0 - HA, oy = ty0 - HA, oz = tz0 - HA;

    const float* img = image + ((size_t)b << 21);
    int t = threadIdx.x;          // 0..1023

    // ---- thread -> 4 consecutive z voxels ----
    int zq = (t & 3) << 2;        // 0,4,8,12
    int ly = (t >> 2) & 15;
    int lx = t >> 6;
    int vx = tx0 + lx, vy = ty0 + ly, vz = tz0 + zq;
    int lin0 = (vx << 14) + (vy << 7) + vz;      // 16B aligned

    // ddf prefetch: 3 vector loads (issue before staging; used after barrier)
    const float* ddfb = ddf + (size_t)b * 3 * N;
    fvec4 dx4 = *(const fvec4*)(ddfb + lin0);
    fvec4 dy4 = *(const fvec4*)(ddfb + lin0 + N);
    fvec4 dz4 = *(const fvec4*)(ddfb + lin0 + 2 * N);

    // ---- stage 32^3 region as fp16 (zeros outside volume) ----
    // 4096 32-byte slots; slot s: row = s>>2 (rx*32+ry), zo = (s&3)*8.
    // oz ≡ 0 mod 8 -> each 8-float chunk is fully inside or fully outside.
    fvec4 sa[4], sb[4];
    int rows[4], zos[4];
#pragma unroll
    for (int c = 0; c < 4; ++c) {
        int s   = c * 1024 + t;
        int row = s >> 2;
        int zo  = (s & 3) << 3;
        rows[c] = row; zos[c] = zo;
        int gx = ox + (row >> 5);
        int gy = oy + (row & 31);
        int gz = oz + zo;
        bool ok = ((unsigned)gx < 128u) & ((unsigned)gy < 128u) & ((unsigned)gz < 121u);
        const float* p = img + (gx << 14) + (gy << 7) + gz;
        fvec4 z4 = {0.f, 0.f, 0.f, 0.f};
        sa[c] = ok ? *(const fvec4*)p       : z4;
        sb[c] = ok ? *(const fvec4*)(p + 4) : z4;
    }
    unsigned short* tp = (unsigned short*)tile;
#pragma unroll
    for (int c = 0; c < 4; ++c) {
        __half2 h0 = __floats2half2_rn(sa[c].x, sa[c].y);
        __half2 h1 = __floats2half2_rn(sa[c].z, sa[c].w);
        __half2 h2 = __floats2half2_rn(sb[c].x, sb[c].y);
        __half2 h3 = __floats2half2_rn(sb[c].z, sb[c].w);
        uint4 pk;
        pk.x = *(unsigned int*)&h0;
        pk.y = *(unsigned int*)&h1;
        pk.z = *(unsigned int*)&h2;
        pk.w = *(unsigned int*)&h3;
        *(uint4*)(tp + rows[c] * 32 + zos[c]) = pk;   // ds_write_b128
    }
    __syncthreads();

    // ---- compute 4 outputs (consecutive z), one float4 store ----
    float* outb = out + ((size_t)b << 21);
    const unsigned int* cells = (const unsigned int*)tile;   // half2 cells, 4B
    float dxp[4] = {dx4.x, dx4.y, dx4.z, dx4.w};
    float dyp[4] = {dy4.x, dy4.y, dy4.z, dy4.w};
    float dzp[4] = {dz4.x, dz4.y, dz4.z, dz4.w};
    float res[4];

#pragma unroll
    for (int i = 0; i < 4; ++i) {
        float x = (float)vx + dxp[i];
        float y = (float)vy + dyp[i];
        float z = (float)(vz + i) + dzp[i];

        float xf = floorf(x), yf = floorf(y), zf = floorf(z);
        float fx = x - xf, fy = y - yf, fz = z - zf;
        int x0 = (int)xf, y0 = (int)yf, z0 = (int)zf;
        int rx = x0 - ox, ry = y0 - oy, rz = z0 - oz;

        float acc;
        if ((unsigned)rx <= 30u && (unsigned)ry <= 30u && (unsigned)rz <= 30u) {
            // fast path: staged zeros implement zero-padding exactly.
            // z-pair (rz, rz+1) always inside cells c, c+1 of the row
            // (cross-row cell c+1 is only read, never used, when rz even).
            int rowc = ((rx << 5) + ry) << 4;   // row * 16 cells
            int c  = rowc + (rz >> 1);
            int sh = (rz & 1) << 4;
            unsigned l00 = cells[c];
            unsigned h00 = cells[c + 1];
            unsigned l01 = cells[c + 16];
            unsigned h01 = cells[c + 17];
            unsigned l10 = cells[c + 512];
            unsigned h10 = cells[c + 513];
            unsigned l11 = cells[c + 528];
            unsigned h11 = cells[c + 529];

            float az0 = 1.f - fz;
            float zz[4];
            unsigned los[4] = {l00, l01, l10, l11};
            unsigned his[4] = {h00, h01, h10, h11};
#pragma unroll
            for (int p2 = 0; p2 < 4; ++p2) {
                unsigned long long v = ((unsigned long long)his[p2] << 32) | los[p2];
                unsigned pr = (unsigned)(v >> sh);
                __half2 hp = *(__half2*)&pr;
                float2 f2 = __half22float2(hp);
                zz[p2] = az0 * f2.x + fz * f2.y;
            }
            float ay0 = 1.f - fy;
            acc = (1.f - fx) * (ay0 * zz[0] + fy * zz[1]) +
                  fx         * (ay0 * zz[2] + fy * zz[3]);
        } else {
            // rare (~0.1%): exact fp32 global gather with zero-padding.
            int x1 = x0 + 1, y1 = y0 + 1, z1 = z0 + 1;
            bool vx0 = (unsigned)x0 < (unsigned)H;
            bool vx1 = (unsigned)x1 < (unsigned)H;
            bool vy0 = (unsigned)y0 < (unsigned)W;
            bool vy1 = (unsigned)y1 < (unsigned)W;
            bool vz0 = (unsigned)z0 < (unsigned)D;
            bool vz1 = (unsigned)z1 < (unsigned)D;
            float ax0 = vx0 ? (1.0f - fx) : 0.0f;
            float ax1 = vx1 ? fx          : 0.0f;
            float ay0 = vy0 ? (1.0f - fy) : 0.0f;
            float ay1 = vy1 ? fy          : 0.0f;
            float az0 = vz0 ? (1.0f - fz) : 0.0f;
            float az1 = vz1 ? fz          : 0.0f;
            int cx0 = vx0 ? x0 : 0;
            int cx1 = vx1 ? x1 : 0;
            int cy0 = vy0 ? y0 : 0;
            int cy1 = vy1 ? y1 : 0;
            int cz0 = vz0 ? z0 : 0;
            int cz1 = vz1 ? z1 : 0;
            int rx0 = cx0 << 14, rx1 = cx1 << 14;
            int ry0 = cy0 << 7,  ry1 = cy1 << 7;
            float v000 = img[rx0 + ry0 + cz0];
            float v001 = img[rx0 + ry0 + cz1];
            float v010 = img[rx0 + ry1 + cz0];
            float v011 = img[rx0 + ry1 + cz1];
            float v100 = img[rx1 + ry0 + cz0];
            float v101 = img[rx1 + ry0 + cz1];
            float v110 = img[rx1 + ry1 + cz0];
            float v111 = img[rx1 + ry1 + cz1];
            acc = ax0 * (ay0 * (az0 * v000 + az1 * v001) +
                         ay1 * (az0 * v010 + az1 * v011)) +
                  ax1 * (ay0 * (az0 * v100 + az1 * v101) +
                         ay1 * (az0 * v110 + az1 * v111));
        }
        res[i] = acc;
    }
    fvec4 r4 = {res[0], res[1], res[2], res[3]};
    __builtin_nontemporal_store(r4, (fvec4*)(outb + lin0));
}

extern "C" void kernel_launch(void* const* d_in, const int* in_sizes, int n_in,
                              void* d_out, int out_size, void* d_ws, size_t ws_size,
                              hipStream_t stream) {
    const float* image = (const float*)d_in[0];
    const float* ddf   = (const float*)d_in[1];
    float* out = (float*)d_out;

    warp_tile_kernel<<<B * 512, 1024, 0, stream>>>(image, ddf, out);
}